// Round 1
// baseline (675.298 us; speedup 1.0000x reference)
//
#include <hip/hip_runtime.h>
#include <hip/hip_bf16.h>
#include <hip/hip_fp16.h>

#define N_TOKENS 16384
#define D_IN 768
#define N_EXPERTS 8
#define EXPERT_DIM 2048

typedef _Float16 half8 __attribute__((ext_vector_type(8)));
typedef _Float16 half4v __attribute__((ext_vector_type(4)));
typedef float floatx4 __attribute__((ext_vector_type(4)));

#define BM 128
#define BN 128
#define BK 32
#define LDA 40   // 32 + 8 pad: 80B row stride -> 20-bank step -> only 2-way aliasing (free)

// ---------------- Router: logits -> softmax max prob + argmax + bucket count ----------------
__global__ __launch_bounds__(256) void router_kernel(const float* __restrict__ act,
    const float* __restrict__ router_b, const float* __restrict__ router,
    float* __restrict__ prob, int* __restrict__ pos, int* __restrict__ eidx,
    int* __restrict__ counts)
{
    int wave = threadIdx.x >> 6, lane = threadIdx.x & 63;
    int t = blockIdx.x * 4 + wave;
    float acc[8];
#pragma unroll
    for (int e = 0; e < 8; ++e) acc[e] = 0.f;
    const float* arow = act + (size_t)t * D_IN;
    for (int i = lane; i < D_IN; i += 64) {
        float a = arow[i] - router_b[i];
        const float* r = router + i * 8;
#pragma unroll
        for (int e = 0; e < 8; ++e) acc[e] += a * r[e];
    }
#pragma unroll
    for (int s = 32; s > 0; s >>= 1) {
#pragma unroll
        for (int e = 0; e < 8; ++e) acc[e] += __shfl_down(acc[e], s, 64);
    }
    if (lane == 0) {
        float m = acc[0]; int ai = 0;
#pragma unroll
        for (int e = 1; e < 8; ++e) if (acc[e] > m) { m = acc[e]; ai = e; }  // first-max like argmax
        float s = 0.f;
#pragma unroll
        for (int e = 0; e < 8; ++e) s += __expf(acc[e] - m);
        prob[t] = 1.0f / s;     // softmax prob of the max logit
        eidx[t] = ai;
        pos[t] = atomicAdd(&counts[ai], 1);
    }
}

__global__ void scan_kernel(const int* __restrict__ counts, int* __restrict__ offsets)
{
    if (threadIdx.x == 0) {
        int s = 0;
        for (int e = 0; e < N_EXPERTS; ++e) { offsets[e] = s; s += counts[e]; }
    }
}

__global__ __launch_bounds__(256) void order_kernel(const int* __restrict__ eidx,
    const int* __restrict__ pos, const int* __restrict__ offsets, int* __restrict__ order)
{
    int t = blockIdx.x * 256 + threadIdx.x;
    order[offsets[eidx[t]] + pos[t]] = t;
}

// ---------------- Weight transpose fp32 [E][K][Nc] -> f16 [E][Nc][K] ----------------
__global__ __launch_bounds__(256) void transpose_to_half(const float* __restrict__ W,
    _Float16* __restrict__ WT, int K, int Nc)
{
    __shared__ _Float16 tile[64][72];
    size_t esz = (size_t)K * Nc;
    const float* We = W + (size_t)blockIdx.z * esz;
    _Float16* WTe = WT + (size_t)blockIdx.z * esz;
    int n0 = blockIdx.x * 64, k0 = blockIdx.y * 64;
    int tr = threadIdx.x >> 4;   // 0..15 (k row within pass)
    int tc = threadIdx.x & 15;   // col quad (4 floats)
#pragma unroll
    for (int rr = 0; rr < 64; rr += 16) {
        int k = k0 + rr + tr;
        float4 v = *(const float4*)(We + (size_t)k * Nc + n0 + tc * 4);
        tile[tc * 4 + 0][rr + tr] = (_Float16)v.x;
        tile[tc * 4 + 1][rr + tr] = (_Float16)v.y;
        tile[tc * 4 + 2][rr + tr] = (_Float16)v.z;
        tile[tc * 4 + 3][rr + tr] = (_Float16)v.w;
    }
    __syncthreads();
#pragma unroll
    for (int p = 0; p < 2; ++p) {
        int id = threadIdx.x + p * 256;  // 0..511
        int r = id >> 3, ch = id & 7;
        half8 v = *(const half8*)&tile[r][ch * 8];
        *(half8*)(WTe + (size_t)(n0 + r) * K + k0 + ch * 8) = v;
    }
}

// ---------------- Encode GEMM: latent[slot] = relu(act[order[slot]] @ enc[e]) ----------------
__global__ __launch_bounds__(256) void encode_kernel(const float* __restrict__ act,
    const _Float16* __restrict__ encT, const int* __restrict__ order,
    const int* __restrict__ counts, const int* __restrict__ offsets,
    _Float16* __restrict__ latent)
{
    int e = blockIdx.z;
    int n_e = counts[e];
    int mt = blockIdx.y;
    if (mt * BM >= n_e) return;
    int nt = blockIdx.x;
    int slot0 = offsets[e] + mt * BM;
    int mrem = n_e - mt * BM;

    __shared__ _Float16 As[BM][LDA];
    __shared__ _Float16 Bs[BN][LDA];
    __shared__ int s_tok[BM];

    int tid = threadIdx.x;
    if (tid < BM) s_tok[tid] = (tid < mrem) ? order[slot0 + tid] : -1;
    __syncthreads();

    const _Float16* Be = encT + (size_t)e * D_IN * EXPERT_DIM + (size_t)(nt * BN) * D_IN;

    int wave = tid >> 6, lane = tid & 63;
    int wm = wave >> 1, wn = wave & 1;
    floatx4 acc[4][4];
#pragma unroll
    for (int i = 0; i < 4; ++i)
#pragma unroll
        for (int j = 0; j < 4; ++j) acc[i][j] = (floatx4){0.f, 0.f, 0.f, 0.f};

    for (int k0 = 0; k0 < D_IN; k0 += BK) {
        // stage A: gathered fp32 -> f16, 128 x 32
#pragma unroll
        for (int p = 0; p < 4; ++p) {
            int id = tid + p * 256;       // 0..1023
            int r = id >> 3, cq = id & 7; // row, 4-float chunk
            int tok = s_tok[r];
            half4v hv = {(_Float16)0, (_Float16)0, (_Float16)0, (_Float16)0};
            if (tok >= 0) {
                float4 v = *(const float4*)(act + (size_t)tok * D_IN + k0 + cq * 4);
                hv[0] = (_Float16)v.x; hv[1] = (_Float16)v.y;
                hv[2] = (_Float16)v.z; hv[3] = (_Float16)v.w;
            }
            *(half4v*)&As[r][cq * 4] = hv;
        }
        // stage B: f16 contiguous, 128 x 32
#pragma unroll
        for (int p = 0; p < 2; ++p) {
            int id = tid + p * 256;       // 0..511
            int r = id >> 2, ch = id & 3;
            half8 v = *(const half8*)(Be + (size_t)r * D_IN + k0 + ch * 8);
            *(half8*)&Bs[r][ch * 8] = v;
        }
        __syncthreads();
        half8 af[4], bf[4];
        int mrow = lane & 15, kq = (lane >> 4) * 8;
#pragma unroll
        for (int i = 0; i < 4; ++i) af[i] = *(const half8*)&As[wm * 64 + i * 16 + mrow][kq];
#pragma unroll
        for (int i = 0; i < 4; ++i) bf[i] = *(const half8*)&Bs[wn * 64 + i * 16 + mrow][kq];
#pragma unroll
        for (int i = 0; i < 4; ++i)
#pragma unroll
            for (int j = 0; j < 4; ++j)
                acc[i][j] = __builtin_amdgcn_mfma_f32_16x16x32_f16(af[i], bf[j], acc[i][j], 0, 0, 0);
        __syncthreads();
    }

    int crow_base = wm * 64 + (lane >> 4) * 4;
    int ccol_base = nt * BN + wn * 64 + (lane & 15);
#pragma unroll
    for (int i = 0; i < 4; ++i) {
#pragma unroll
        for (int j = 0; j < 4; ++j) {
#pragma unroll
            for (int r = 0; r < 4; ++r) {
                int row = crow_base + i * 16 + r;
                if (row < mrem) {
                    float v = acc[i][j][r];
                    v = v > 0.f ? v : 0.f;
                    latent[(size_t)(slot0 + row) * EXPERT_DIM + ccol_base + j * 16] = (_Float16)v;
                }
            }
        }
    }
}

// ---------------- Decode GEMM: out[tok] = prob[tok] * (latent[slot] @ dec[e]) + pre_b ----------------
__global__ __launch_bounds__(256) void decode_kernel(const _Float16* __restrict__ latent,
    const _Float16* __restrict__ decT, const int* __restrict__ order,
    const int* __restrict__ counts, const int* __restrict__ offsets,
    const float* __restrict__ prob, const float* __restrict__ pre_b,
    float* __restrict__ out)
{
    int e = blockIdx.z;
    int n_e = counts[e];
    int mt = blockIdx.y;
    if (mt * BM >= n_e) return;
    int nt = blockIdx.x;     // 0..5 (768/128)
    int slot0 = offsets[e] + mt * BM;
    int mrem = n_e - mt * BM;

    __shared__ _Float16 As[BM][LDA];
    __shared__ _Float16 Bs[BN][LDA];
    __shared__ int s_tok[BM];
    __shared__ float s_p[BM];

    int tid = threadIdx.x;
    if (tid < BM) {
        int tok = (tid < mrem) ? order[slot0 + tid] : 0;
        s_tok[tid] = tok;
        s_p[tid] = prob[tok];
    }

    const _Float16* Be = decT + (size_t)e * EXPERT_DIM * D_IN + (size_t)(nt * BN) * EXPERT_DIM;

    int wave = tid >> 6, lane = tid & 63;
    int wm = wave >> 1, wn = wave & 1;
    floatx4 acc[4][4];
#pragma unroll
    for (int i = 0; i < 4; ++i)
#pragma unroll
        for (int j = 0; j < 4; ++j) acc[i][j] = (floatx4){0.f, 0.f, 0.f, 0.f};

    for (int k0 = 0; k0 < EXPERT_DIM; k0 += BK) {
        // stage A: dense f16 latent rows, 128 x 32
#pragma unroll
        for (int p = 0; p < 2; ++p) {
            int id = tid + p * 256;
            int r = id >> 2, ch = id & 3;
            half8 v = {(_Float16)0, (_Float16)0, (_Float16)0, (_Float16)0,
                       (_Float16)0, (_Float16)0, (_Float16)0, (_Float16)0};
            if (r < mrem)
                v = *(const half8*)(latent + (size_t)(slot0 + r) * EXPERT_DIM + k0 + ch * 8);
            *(half8*)&As[r][ch * 8] = v;
        }
        // stage B
#pragma unroll
        for (int p = 0; p < 2; ++p) {
            int id = tid + p * 256;
            int r = id >> 2, ch = id & 3;
            half8 v = *(const half8*)(Be + (size_t)r * EXPERT_DIM + k0 + ch * 8);
            *(half8*)&Bs[r][ch * 8] = v;
        }
        __syncthreads();
        half8 af[4], bf[4];
        int mrow = lane & 15, kq = (lane >> 4) * 8;
#pragma unroll
        for (int i = 0; i < 4; ++i) af[i] = *(const half8*)&As[wm * 64 + i * 16 + mrow][kq];
#pragma unroll
        for (int i = 0; i < 4; ++i) bf[i] = *(const half8*)&Bs[wn * 64 + i * 16 + mrow][kq];
#pragma unroll
        for (int i = 0; i < 4; ++i)
#pragma unroll
            for (int j = 0; j < 4; ++j)
                acc[i][j] = __builtin_amdgcn_mfma_f32_16x16x32_f16(af[i], bf[j], acc[i][j], 0, 0, 0);
        __syncthreads();
    }

    int crow_base = wm * 64 + (lane >> 4) * 4;
    int ccol_base = nt * BN + wn * 64 + (lane & 15);
#pragma unroll
    for (int i = 0; i < 4; ++i) {
#pragma unroll
        for (int j = 0; j < 4; ++j) {
            int col = ccol_base + j * 16;
            float pb = pre_b[col];
#pragma unroll
            for (int r = 0; r < 4; ++r) {
                int row = crow_base + i * 16 + r;
                if (row < mrem) {
                    out[(size_t)s_tok[row] * D_IN + col] = s_p[row] * acc[i][j][r] + pb;
                }
            }
        }
    }
}

extern "C" void kernel_launch(void* const* d_in, const int* in_sizes, int n_in,
                              void* d_out, int out_size, void* d_ws, size_t ws_size,
                              hipStream_t stream)
{
    const float* act      = (const float*)d_in[0];
    const float* pre_b    = (const float*)d_in[1];
    const float* enc      = (const float*)d_in[2];
    const float* dec      = (const float*)d_in[3];
    const float* router_b = (const float*)d_in[4];
    const float* router   = (const float*)d_in[5];
    float* out = (float*)d_out;

    char* w = (char*)d_ws;
    int* counts  = (int*)w;  w += 256;
    int* offsets = (int*)w;  w += 256;
    int* eidx    = (int*)w;  w += N_TOKENS * 4;
    int* pos     = (int*)w;  w += N_TOKENS * 4;
    int* order   = (int*)w;  w += N_TOKENS * 4;
    float* prob  = (float*)w; w += N_TOKENS * 4;
    _Float16* encT   = (_Float16*)w; w += (size_t)N_EXPERTS * D_IN * EXPERT_DIM * 2;
    _Float16* decT   = (_Float16*)w; w += (size_t)N_EXPERTS * D_IN * EXPERT_DIM * 2;
    _Float16* latent = (_Float16*)w; w += (size_t)N_TOKENS * EXPERT_DIM * 2;

    hipMemsetAsync(counts, 0, N_EXPERTS * sizeof(int), stream);

    router_kernel<<<N_TOKENS / 4, 256, 0, stream>>>(act, router_b, router, prob, pos, eidx, counts);
    scan_kernel<<<1, 64, 0, stream>>>(counts, offsets);
    order_kernel<<<N_TOKENS / 256, 256, 0, stream>>>(eidx, pos, offsets, order);

    // enc: [E][768][2048] -> encT [E][2048][768]
    transpose_to_half<<<dim3(EXPERT_DIM / 64, D_IN / 64, N_EXPERTS), 256, 0, stream>>>(enc, encT, D_IN, EXPERT_DIM);
    // dec: [E][2048][768] -> decT [E][768][2048]
    transpose_to_half<<<dim3(D_IN / 64, EXPERT_DIM / 64, N_EXPERTS), 256, 0, stream>>>(dec, decT, EXPERT_DIM, D_IN);

    encode_kernel<<<dim3(EXPERT_DIM / BN, N_TOKENS / BM, N_EXPERTS), 256, 0, stream>>>(
        act, encT, order, counts, offsets, latent);
    decode_kernel<<<dim3(D_IN / BN, N_TOKENS / BM, N_EXPERTS), 256, 0, stream>>>(
        latent, decT, order, counts, offsets, prob, pre_b, out);
}

// Round 2
// 504.812 us; speedup vs baseline: 1.3377x; 1.3377x over previous
//
#include <hip/hip_runtime.h>
#include <hip/hip_bf16.h>
#include <hip/hip_fp16.h>

#define N_TOKENS 16384
#define D_IN 768
#define N_EXPERTS 8
#define EXPERT_DIM 2048

#define ROUTER_BLOCKS 256           // 64 tokens per block
#define TOK_PER_BLOCK 64

typedef _Float16 half8 __attribute__((ext_vector_type(8)));
typedef _Float16 half4v __attribute__((ext_vector_type(4)));
typedef float floatx4 __attribute__((ext_vector_type(4)));

#define BM 128
#define BN 128
#define BK 32
#define LDA 40   // 32 + 8 pad: 80B row stride -> 20-bank step -> only 2-way aliasing (free)

// ---------------- Phase 1: logits -> prob/eidx + per-block histogram + local pos ----------------
// No global atomics (the 201us lesson: 16384 value-returning atomicAdds on 8
// words serialized in L2). LDS atomics only; one 8-int histogram per block.
__global__ __launch_bounds__(256) void router_kernel(const float* __restrict__ act,
    const float* __restrict__ router_b, const float* __restrict__ router,
    float* __restrict__ prob, int* __restrict__ localpos, int* __restrict__ eidx,
    int* __restrict__ hist /* [ROUTER_BLOCKS][8] */)
{
    __shared__ int h[N_EXPERTS];
    if (threadIdx.x < N_EXPERTS) h[threadIdx.x] = 0;
    __syncthreads();

    int wave = threadIdx.x >> 6, lane = threadIdx.x & 63;
#pragma unroll 1
    for (int it = 0; it < 16; ++it) {
        int t = blockIdx.x * TOK_PER_BLOCK + wave * 16 + it;
        float acc[8];
#pragma unroll
        for (int e = 0; e < 8; ++e) acc[e] = 0.f;
        const float* arow = act + (size_t)t * D_IN;
#pragma unroll
        for (int i0 = 0; i0 < D_IN; i0 += 64) {
            int i = i0 + lane;
            float a = arow[i] - router_b[i];
            const float* r = router + i * 8;
#pragma unroll
            for (int e = 0; e < 8; ++e) acc[e] += a * r[e];
        }
#pragma unroll
        for (int s = 32; s > 0; s >>= 1) {
#pragma unroll
            for (int e = 0; e < 8; ++e) acc[e] += __shfl_down(acc[e], s, 64);
        }
        if (lane == 0) {
            float m = acc[0]; int ai = 0;
#pragma unroll
            for (int e = 1; e < 8; ++e) if (acc[e] > m) { m = acc[e]; ai = e; }  // first-max = jnp.argmax
            float s = 0.f;
#pragma unroll
            for (int e = 0; e < 8; ++e) s += __expf(acc[e] - m);
            prob[t] = 1.0f / s;              // softmax prob of the argmax logit
            eidx[t] = ai;
            localpos[t] = atomicAdd(&h[ai], 1);   // LDS atomic: fast
        }
    }
    __syncthreads();
    if (threadIdx.x < N_EXPERTS) hist[blockIdx.x * N_EXPERTS + threadIdx.x] = h[threadIdx.x];
}

// ---------------- Phase 2: scan histograms -> per-(block,expert) base, counts, offsets ----------------
__global__ __launch_bounds__(256) void scan_kernel(int* __restrict__ hist,
    int* __restrict__ counts, int* __restrict__ offsets)
{
    __shared__ int sh[ROUTER_BLOCKS * N_EXPERTS];
    __shared__ int tot[N_EXPERTS], off[N_EXPERTS];
    int tid = threadIdx.x;
    // load: thread b owns block b's 8-entry row
    *(int4*)&sh[tid * 8]     = *(const int4*)&hist[tid * 8];
    *(int4*)&sh[tid * 8 + 4] = *(const int4*)&hist[tid * 8 + 4];
    __syncthreads();
    if (tid < N_EXPERTS) {
        int run = 0;
        for (int b = 0; b < ROUTER_BLOCKS; ++b) {
            int v = sh[b * 8 + tid];
            sh[b * 8 + tid] = run;
            run += v;
        }
        tot[tid] = run;
    }
    __syncthreads();
    if (tid == 0) {
        int run = 0;
        for (int e = 0; e < N_EXPERTS; ++e) {
            off[e] = run;
            offsets[e] = run;
            counts[e] = tot[e];
            run += tot[e];
        }
    }
    __syncthreads();
    int4 a = *(const int4*)&sh[tid * 8];
    int4 b = *(const int4*)&sh[tid * 8 + 4];
    a.x += off[0]; a.y += off[1]; a.z += off[2]; a.w += off[3];
    b.x += off[4]; b.y += off[5]; b.z += off[6]; b.w += off[7];
    *(int4*)&hist[tid * 8]     = a;   // hist now holds global slot bases
    *(int4*)&hist[tid * 8 + 4] = b;
}

// ---------------- Phase 3: scatter token ids into expert-sorted order ----------------
__global__ __launch_bounds__(256) void order_kernel(const int* __restrict__ eidx,
    const int* __restrict__ localpos, const int* __restrict__ hist,
    int* __restrict__ order)
{
    int t = blockIdx.x * 256 + threadIdx.x;
    int base = hist[(t >> 6) * N_EXPERTS + eidx[t]];
    order[base + localpos[t]] = t;
}

// ---------------- Weight transpose fp32 [E][K][Nc] -> f16 [E][Nc][K] ----------------
__global__ __launch_bounds__(256) void transpose_to_half(const float* __restrict__ W,
    _Float16* __restrict__ WT, int K, int Nc)
{
    __shared__ _Float16 tile[64][72];
    size_t esz = (size_t)K * Nc;
    const float* We = W + (size_t)blockIdx.z * esz;
    _Float16* WTe = WT + (size_t)blockIdx.z * esz;
    int n0 = blockIdx.x * 64, k0 = blockIdx.y * 64;
    int tr = threadIdx.x >> 4;   // 0..15 (k row within pass)
    int tc = threadIdx.x & 15;   // col quad (4 floats)
#pragma unroll
    for (int rr = 0; rr < 64; rr += 16) {
        int k = k0 + rr + tr;
        float4 v = *(const float4*)(We + (size_t)k * Nc + n0 + tc * 4);
        tile[tc * 4 + 0][rr + tr] = (_Float16)v.x;
        tile[tc * 4 + 1][rr + tr] = (_Float16)v.y;
        tile[tc * 4 + 2][rr + tr] = (_Float16)v.z;
        tile[tc * 4 + 3][rr + tr] = (_Float16)v.w;
    }
    __syncthreads();
#pragma unroll
    for (int p = 0; p < 2; ++p) {
        int id = threadIdx.x + p * 256;  // 0..511
        int r = id >> 3, ch = id & 7;
        half8 v = *(const half8*)&tile[r][ch * 8];
        *(half8*)(WTe + (size_t)(n0 + r) * K + k0 + ch * 8) = v;
    }
}

// ---------------- Encode GEMM: latent[slot] = relu(act[order[slot]] @ enc[e]) ----------------
__global__ __launch_bounds__(256) void encode_kernel(const float* __restrict__ act,
    const _Float16* __restrict__ encT, const int* __restrict__ order,
    const int* __restrict__ counts, const int* __restrict__ offsets,
    _Float16* __restrict__ latent)
{
    int e = blockIdx.z;
    int n_e = counts[e];
    int mt = blockIdx.y;
    if (mt * BM >= n_e) return;
    int nt = blockIdx.x;
    int slot0 = offsets[e] + mt * BM;
    int mrem = n_e - mt * BM;

    __shared__ _Float16 As[BM][LDA];
    __shared__ _Float16 Bs[BN][LDA];
    __shared__ int s_tok[BM];

    int tid = threadIdx.x;
    if (tid < BM) s_tok[tid] = (tid < mrem) ? order[slot0 + tid] : -1;
    __syncthreads();

    const _Float16* Be = encT + (size_t)e * D_IN * EXPERT_DIM + (size_t)(nt * BN) * D_IN;

    int wave = tid >> 6, lane = tid & 63;
    int wm = wave >> 1, wn = wave & 1;
    floatx4 acc[4][4];
#pragma unroll
    for (int i = 0; i < 4; ++i)
#pragma unroll
        for (int j = 0; j < 4; ++j) acc[i][j] = (floatx4){0.f, 0.f, 0.f, 0.f};

    for (int k0 = 0; k0 < D_IN; k0 += BK) {
        // stage A: gathered fp32 -> f16, 128 x 32
#pragma unroll
        for (int p = 0; p < 4; ++p) {
            int id = tid + p * 256;       // 0..1023
            int r = id >> 3, cq = id & 7; // row, 4-float chunk
            int tok = s_tok[r];
            half4v hv = {(_Float16)0, (_Float16)0, (_Float16)0, (_Float16)0};
            if (tok >= 0) {
                float4 v = *(const float4*)(act + (size_t)tok * D_IN + k0 + cq * 4);
                hv[0] = (_Float16)v.x; hv[1] = (_Float16)v.y;
                hv[2] = (_Float16)v.z; hv[3] = (_Float16)v.w;
            }
            *(half4v*)&As[r][cq * 4] = hv;
        }
        // stage B: f16 contiguous, 128 x 32
#pragma unroll
        for (int p = 0; p < 2; ++p) {
            int id = tid + p * 256;       // 0..511
            int r = id >> 2, ch = id & 3;
            half8 v = *(const half8*)(Be + (size_t)r * D_IN + k0 + ch * 8);
            *(half8*)&Bs[r][ch * 8] = v;
        }
        __syncthreads();
        half8 af[4], bf[4];
        int mrow = lane & 15, kq = (lane >> 4) * 8;
#pragma unroll
        for (int i = 0; i < 4; ++i) af[i] = *(const half8*)&As[wm * 64 + i * 16 + mrow][kq];
#pragma unroll
        for (int i = 0; i < 4; ++i) bf[i] = *(const half8*)&Bs[wn * 64 + i * 16 + mrow][kq];
#pragma unroll
        for (int i = 0; i < 4; ++i)
#pragma unroll
            for (int j = 0; j < 4; ++j)
                acc[i][j] = __builtin_amdgcn_mfma_f32_16x16x32_f16(af[i], bf[j], acc[i][j], 0, 0, 0);
        __syncthreads();
    }

    int crow_base = wm * 64 + (lane >> 4) * 4;
    int ccol_base = nt * BN + wn * 64 + (lane & 15);
#pragma unroll
    for (int i = 0; i < 4; ++i) {
#pragma unroll
        for (int j = 0; j < 4; ++j) {
#pragma unroll
            for (int r = 0; r < 4; ++r) {
                int row = crow_base + i * 16 + r;
                if (row < mrem) {
                    float v = acc[i][j][r];
                    v = v > 0.f ? v : 0.f;
                    latent[(size_t)(slot0 + row) * EXPERT_DIM + ccol_base + j * 16] = (_Float16)v;
                }
            }
        }
    }
}

// ---------------- Decode GEMM: out[tok] = prob[tok] * (latent[slot] @ dec[e]) + pre_b ----------------
__global__ __launch_bounds__(256) void decode_kernel(const _Float16* __restrict__ latent,
    const _Float16* __restrict__ decT, const int* __restrict__ order,
    const int* __restrict__ counts, const int* __restrict__ offsets,
    const float* __restrict__ prob, const float* __restrict__ pre_b,
    float* __restrict__ out)
{
    int e = blockIdx.z;
    int n_e = counts[e];
    int mt = blockIdx.y;
    if (mt * BM >= n_e) return;
    int nt = blockIdx.x;     // 0..5 (768/128)
    int slot0 = offsets[e] + mt * BM;
    int mrem = n_e - mt * BM;

    __shared__ _Float16 As[BM][LDA];
    __shared__ _Float16 Bs[BN][LDA];
    __shared__ int s_tok[BM];
    __shared__ float s_p[BM];

    int tid = threadIdx.x;
    if (tid < BM) {
        int tok = (tid < mrem) ? order[slot0 + tid] : 0;
        s_tok[tid] = tok;
        s_p[tid] = prob[tok];
    }

    const _Float16* Be = decT + (size_t)e * EXPERT_DIM * D_IN + (size_t)(nt * BN) * EXPERT_DIM;

    int wave = tid >> 6, lane = tid & 63;
    int wm = wave >> 1, wn = wave & 1;
    floatx4 acc[4][4];
#pragma unroll
    for (int i = 0; i < 4; ++i)
#pragma unroll
        for (int j = 0; j < 4; ++j) acc[i][j] = (floatx4){0.f, 0.f, 0.f, 0.f};

    for (int k0 = 0; k0 < EXPERT_DIM; k0 += BK) {
        // stage A: dense f16 latent rows, 128 x 32
#pragma unroll
        for (int p = 0; p < 2; ++p) {
            int id = tid + p * 256;
            int r = id >> 2, ch = id & 3;
            half8 v = {(_Float16)0, (_Float16)0, (_Float16)0, (_Float16)0,
                       (_Float16)0, (_Float16)0, (_Float16)0, (_Float16)0};
            if (r < mrem)
                v = *(const half8*)(latent + (size_t)(slot0 + r) * EXPERT_DIM + k0 + ch * 8);
            *(half8*)&As[r][ch * 8] = v;
        }
        // stage B
#pragma unroll
        for (int p = 0; p < 2; ++p) {
            int id = tid + p * 256;
            int r = id >> 2, ch = id & 3;
            half8 v = *(const half8*)(Be + (size_t)r * EXPERT_DIM + k0 + ch * 8);
            *(half8*)&Bs[r][ch * 8] = v;
        }
        __syncthreads();
        half8 af[4], bf[4];
        int mrow = lane & 15, kq = (lane >> 4) * 8;
#pragma unroll
        for (int i = 0; i < 4; ++i) af[i] = *(const half8*)&As[wm * 64 + i * 16 + mrow][kq];
#pragma unroll
        for (int i = 0; i < 4; ++i) bf[i] = *(const half8*)&Bs[wn * 64 + i * 16 + mrow][kq];
#pragma unroll
        for (int i = 0; i < 4; ++i)
#pragma unroll
            for (int j = 0; j < 4; ++j)
                acc[i][j] = __builtin_amdgcn_mfma_f32_16x16x32_f16(af[i], bf[j], acc[i][j], 0, 0, 0);
        __syncthreads();
    }

    int crow_base = wm * 64 + (lane >> 4) * 4;
    int ccol_base = nt * BN + wn * 64 + (lane & 15);
#pragma unroll
    for (int i = 0; i < 4; ++i) {
#pragma unroll
        for (int j = 0; j < 4; ++j) {
            int col = ccol_base + j * 16;
            float pb = pre_b[col];
#pragma unroll
            for (int r = 0; r < 4; ++r) {
                int row = crow_base + i * 16 + r;
                if (row < mrem) {
                    out[(size_t)s_tok[row] * D_IN + col] = s_p[row] * acc[i][j][r] + pb;
                }
            }
        }
    }
}

extern "C" void kernel_launch(void* const* d_in, const int* in_sizes, int n_in,
                              void* d_out, int out_size, void* d_ws, size_t ws_size,
                              hipStream_t stream)
{
    const float* act      = (const float*)d_in[0];
    const float* pre_b    = (const float*)d_in[1];
    const float* enc      = (const float*)d_in[2];
    const float* dec      = (const float*)d_in[3];
    const float* router_b = (const float*)d_in[4];
    const float* router   = (const float*)d_in[5];
    float* out = (float*)d_out;

    char* w = (char*)d_ws;
    int* counts  = (int*)w;  w += 256;
    int* offsets = (int*)w;  w += 256;
    int* hist    = (int*)w;  w += ROUTER_BLOCKS * N_EXPERTS * 4;
    int* eidx    = (int*)w;  w += N_TOKENS * 4;
    int* lpos    = (int*)w;  w += N_TOKENS * 4;
    int* order   = (int*)w;  w += N_TOKENS * 4;
    float* prob  = (float*)w; w += N_TOKENS * 4;
    _Float16* encT   = (_Float16*)w; w += (size_t)N_EXPERTS * D_IN * EXPERT_DIM * 2;
    _Float16* decT   = (_Float16*)w; w += (size_t)N_EXPERTS * D_IN * EXPERT_DIM * 2;
    _Float16* latent = (_Float16*)w; w += (size_t)N_TOKENS * EXPERT_DIM * 2;

    // enc: [E][768][2048] -> encT [E][2048][768] ; dec: [E][2048][768] -> decT [E][768][2048]
    transpose_to_half<<<dim3(EXPERT_DIM / 64, D_IN / 64, N_EXPERTS), 256, 0, stream>>>(enc, encT, D_IN, EXPERT_DIM);
    transpose_to_half<<<dim3(D_IN / 64, EXPERT_DIM / 64, N_EXPERTS), 256, 0, stream>>>(dec, decT, EXPERT_DIM, D_IN);

    router_kernel<<<ROUTER_BLOCKS, 256, 0, stream>>>(act, router_b, router, prob, lpos, eidx, hist);
    scan_kernel<<<1, 256, 0, stream>>>(hist, counts, offsets);
    order_kernel<<<N_TOKENS / 256, 256, 0, stream>>>(eidx, lpos, hist, order);

    encode_kernel<<<dim3(EXPERT_DIM / BN, N_TOKENS / BM, N_EXPERTS), 256, 0, stream>>>(
        act, encT, order, counts, offsets, latent);
    decode_kernel<<<dim3(D_IN / BN, N_TOKENS / BM, N_EXPERTS), 256, 0, stream>>>(
        latent, decT, order, counts, offsets, prob, pre_b, out);
}

// Round 3
// 430.665 us; speedup vs baseline: 1.5680x; 1.1722x over previous
//
#include <hip/hip_runtime.h>
#include <hip/hip_bf16.h>
#include <hip/hip_fp16.h>

#define N_TOKENS 16384
#define D_IN 768
#define N_EXPERTS 8
#define EXPERT_DIM 2048

#define ROUTER_BLOCKS 256           // 64 tokens per block
#define TOK_PER_BLOCK 64

typedef _Float16 half8 __attribute__((ext_vector_type(8)));
typedef float floatx4 __attribute__((ext_vector_type(4)));

#define BM 128
#define BN 128
#define BK 32
// LDS tiles are UNPADDED 128x32 halves (64B rows). Swizzle: 16B chunk c of row r
// is stored at chunk (c + (r>>1)) & 3. -> frag ds_read_b128: each 8-lane group
// covers all 32 banks once (conflict-free); staging writes are lane-sequential.

__device__ __forceinline__ void glds16(const _Float16* g, _Float16* l) {
    __builtin_amdgcn_global_load_lds(
        (const __attribute__((address_space(1))) unsigned int*)g,
        (__attribute__((address_space(3))) unsigned int*)l, 16, 0, 0);
}

// ---------------- Phase 1: logits -> prob/eidx + per-block histogram + local pos ----------------
__global__ __launch_bounds__(256) void router_kernel(const float* __restrict__ act,
    const float* __restrict__ router_b, const float* __restrict__ router,
    float* __restrict__ prob, int* __restrict__ localpos, int* __restrict__ eidx,
    int* __restrict__ hist /* [ROUTER_BLOCKS][8] */)
{
    __shared__ int h[N_EXPERTS];
    if (threadIdx.x < N_EXPERTS) h[threadIdx.x] = 0;
    __syncthreads();

    int wave = threadIdx.x >> 6, lane = threadIdx.x & 63;
#pragma unroll 1
    for (int it = 0; it < 16; ++it) {
        int t = blockIdx.x * TOK_PER_BLOCK + wave * 16 + it;
        float acc[8];
#pragma unroll
        for (int e = 0; e < 8; ++e) acc[e] = 0.f;
        const float* arow = act + (size_t)t * D_IN;
#pragma unroll
        for (int i0 = 0; i0 < D_IN; i0 += 64) {
            int i = i0 + lane;
            float a = arow[i] - router_b[i];
            const float* r = router + i * 8;
#pragma unroll
            for (int e = 0; e < 8; ++e) acc[e] += a * r[e];
        }
#pragma unroll
        for (int s = 32; s > 0; s >>= 1) {
#pragma unroll
            for (int e = 0; e < 8; ++e) acc[e] += __shfl_down(acc[e], s, 64);
        }
        if (lane == 0) {
            float m = acc[0]; int ai = 0;
#pragma unroll
            for (int e = 1; e < 8; ++e) if (acc[e] > m) { m = acc[e]; ai = e; }  // first-max = jnp.argmax
            float s = 0.f;
#pragma unroll
            for (int e = 0; e < 8; ++e) s += __expf(acc[e] - m);
            prob[t] = 1.0f / s;
            eidx[t] = ai;
            localpos[t] = atomicAdd(&h[ai], 1);   // LDS atomic only
        }
    }
    __syncthreads();
    if (threadIdx.x < N_EXPERTS) hist[blockIdx.x * N_EXPERTS + threadIdx.x] = h[threadIdx.x];
}

// ---------------- Phase 2: scan histograms ----------------
__global__ __launch_bounds__(256) void scan_kernel(int* __restrict__ hist,
    int* __restrict__ counts, int* __restrict__ offsets)
{
    __shared__ int sh[ROUTER_BLOCKS * N_EXPERTS];
    __shared__ int tot[N_EXPERTS], off[N_EXPERTS];
    int tid = threadIdx.x;
    *(int4*)&sh[tid * 8]     = *(const int4*)&hist[tid * 8];
    *(int4*)&sh[tid * 8 + 4] = *(const int4*)&hist[tid * 8 + 4];
    __syncthreads();
    if (tid < N_EXPERTS) {
        int run = 0;
        for (int b = 0; b < ROUTER_BLOCKS; ++b) {
            int v = sh[b * 8 + tid];
            sh[b * 8 + tid] = run;
            run += v;
        }
        tot[tid] = run;
    }
    __syncthreads();
    if (tid == 0) {
        int run = 0;
        for (int e = 0; e < N_EXPERTS; ++e) {
            off[e] = run;
            offsets[e] = run;
            counts[e] = tot[e];
            run += tot[e];
        }
    }
    __syncthreads();
    int4 a = *(const int4*)&sh[tid * 8];
    int4 b = *(const int4*)&sh[tid * 8 + 4];
    a.x += off[0]; a.y += off[1]; a.z += off[2]; a.w += off[3];
    b.x += off[4]; b.y += off[5]; b.z += off[6]; b.w += off[7];
    *(int4*)&hist[tid * 8]     = a;
    *(int4*)&hist[tid * 8 + 4] = b;
}

// ---------------- Phase 3: scatter ----------------
__global__ __launch_bounds__(256) void order_kernel(const int* __restrict__ eidx,
    const int* __restrict__ localpos, const int* __restrict__ hist,
    int* __restrict__ order)
{
    int t = blockIdx.x * 256 + threadIdx.x;
    int base = hist[(t >> 6) * N_EXPERTS + eidx[t]];
    order[base + localpos[t]] = t;
}

// ---------------- Weight transpose fp32 [E][K][Nc] -> f16 [E][Nc][K] ----------------
__global__ __launch_bounds__(256) void transpose_to_half(const float* __restrict__ W,
    _Float16* __restrict__ WT, int K, int Nc)
{
    __shared__ _Float16 tile[64][72];
    size_t esz = (size_t)K * Nc;
    const float* We = W + (size_t)blockIdx.z * esz;
    _Float16* WTe = WT + (size_t)blockIdx.z * esz;
    int n0 = blockIdx.x * 64, k0 = blockIdx.y * 64;
    int tr = threadIdx.x >> 4;
    int tc = threadIdx.x & 15;
#pragma unroll
    for (int rr = 0; rr < 64; rr += 16) {
        int k = k0 + rr + tr;
        float4 v = *(const float4*)(We + (size_t)k * Nc + n0 + tc * 4);
        tile[tc * 4 + 0][rr + tr] = (_Float16)v.x;
        tile[tc * 4 + 1][rr + tr] = (_Float16)v.y;
        tile[tc * 4 + 2][rr + tr] = (_Float16)v.z;
        tile[tc * 4 + 3][rr + tr] = (_Float16)v.w;
    }
    __syncthreads();
#pragma unroll
    for (int p = 0; p < 2; ++p) {
        int id = threadIdx.x + p * 256;
        int r = id >> 3, ch = id & 7;
        half8 v = *(const half8*)&tile[r][ch * 8];
        *(half8*)(WTe + (size_t)(n0 + r) * K + k0 + ch * 8) = v;
    }
}

// ---------------- Encode GEMM: latent[slot] = relu(act[order[slot]] @ enc[e]) ----------------
__global__ __launch_bounds__(256) void encode_kernel(const float* __restrict__ act,
    const _Float16* __restrict__ encT, const int* __restrict__ order,
    const int* __restrict__ counts, const int* __restrict__ offsets,
    _Float16* __restrict__ latent)
{
    int e = blockIdx.z;
    int n_e = counts[e];
    int mt = blockIdx.y;
    if (mt * BM >= n_e) return;
    int nt = blockIdx.x;
    int slot0 = offsets[e] + mt * BM;
    int mrem = n_e - mt * BM;

    __shared__ _Float16 As[BM * BK];      // swizzled, unpadded
    __shared__ _Float16 Bs[BN * BK];
    __shared__ int s_tok[BM];

    int tid = threadIdx.x;
    if (tid < BM) s_tok[tid] = (tid < mrem) ? order[slot0 + tid] : -1;
    __syncthreads();

    const _Float16* Be = encT + (size_t)e * D_IN * EXPERT_DIM + (size_t)(nt * BN) * D_IN;

    int wave = tid >> 6, lane = tid & 63;
    int wm = wave >> 1, wn = wave & 1;

    // ---- staging geometry (fixed per thread) ----
    // chunk id = tid + p*256 ; row r = id>>2 ; stored chunk sc = id&3 ;
    // logical chunk c = (sc - (r>>1)) & 3. Note (r+64)>>1 == r>>1 (mod 4), so c is
    // the same for p=0 and p=1.
    int r0 = tid >> 2, sc = tid & 3;
    int c = (sc - (r0 >> 1)) & 3;
    int tokA0 = s_tok[r0], tokA1 = s_tok[r0 + 64];
    const float* pa0 = (tokA0 >= 0) ? act + (size_t)tokA0 * D_IN + c * 8 : nullptr;
    const float* pa1 = (tokA1 >= 0) ? act + (size_t)tokA1 * D_IN + c * 8 : nullptr;
    _Float16* wA0 = &As[r0 * BK + sc * 8];
    _Float16* wA1 = &As[(r0 + 64) * BK + sc * 8];
    // B glds: per-lane global pointer, wave-uniform LDS base
    const _Float16* pb0 = Be + (size_t)r0 * D_IN + c * 8;
    const _Float16* pb1 = Be + (size_t)(r0 + 64) * D_IN + c * 8;
    _Float16* lb0 = &Bs[(wave * 64) * 8];          // lane writes base + lane*16
    _Float16* lb1 = &Bs[(wave * 64 + 256) * 8];

    // frag read swizzle offset: chunk (lane>>4) of row base+ (lane&15)
    int frag_off = ((((lane >> 4) + ((lane & 15) >> 1)) & 3) * 8);
    int mrow = lane & 15;

    floatx4 acc[4][4];
#pragma unroll
    for (int i = 0; i < 4; ++i)
#pragma unroll
        for (int j = 0; j < 4; ++j) acc[i][j] = (floatx4){0.f, 0.f, 0.f, 0.f};

#pragma unroll 1
    for (int k0 = 0; k0 < D_IN; k0 += BK) {
        // async B -> LDS (16B per lane)
        glds16(pb0 + k0, lb0);
        glds16(pb1 + k0, lb1);
        // A: gathered fp32 -> f16, one b128 write per chunk
        half8 h0 = {0, 0, 0, 0, 0, 0, 0, 0}, h1 = {0, 0, 0, 0, 0, 0, 0, 0};
        if (pa0) {
            float4 v0 = *(const float4*)(pa0 + k0);
            float4 v1 = *(const float4*)(pa0 + k0 + 4);
            h0[0] = (_Float16)v0.x; h0[1] = (_Float16)v0.y; h0[2] = (_Float16)v0.z; h0[3] = (_Float16)v0.w;
            h0[4] = (_Float16)v1.x; h0[5] = (_Float16)v1.y; h0[6] = (_Float16)v1.z; h0[7] = (_Float16)v1.w;
        }
        if (pa1) {
            float4 v0 = *(const float4*)(pa1 + k0);
            float4 v1 = *(const float4*)(pa1 + k0 + 4);
            h1[0] = (_Float16)v0.x; h1[1] = (_Float16)v0.y; h1[2] = (_Float16)v0.z; h1[3] = (_Float16)v0.w;
            h1[4] = (_Float16)v1.x; h1[5] = (_Float16)v1.y; h1[6] = (_Float16)v1.z; h1[7] = (_Float16)v1.w;
        }
        *(half8*)wA0 = h0;
        *(half8*)wA1 = h1;
        __syncthreads();

        half8 af[4], bf[4];
#pragma unroll
        for (int i = 0; i < 4; ++i) af[i] = *(const half8*)&As[(wm * 64 + i * 16 + mrow) * BK + frag_off];
#pragma unroll
        for (int i = 0; i < 4; ++i) bf[i] = *(const half8*)&Bs[(wn * 64 + i * 16 + mrow) * BK + frag_off];
#pragma unroll
        for (int i = 0; i < 4; ++i)
#pragma unroll
            for (int j = 0; j < 4; ++j)
                acc[i][j] = __builtin_amdgcn_mfma_f32_16x16x32_f16(af[i], bf[j], acc[i][j], 0, 0, 0);
        __syncthreads();
    }

    int crow_base = wm * 64 + (lane >> 4) * 4;
    int ccol_base = nt * BN + wn * 64 + (lane & 15);
#pragma unroll
    for (int i = 0; i < 4; ++i) {
#pragma unroll
        for (int j = 0; j < 4; ++j) {
#pragma unroll
            for (int r = 0; r < 4; ++r) {
                int row = crow_base + i * 16 + r;
                if (row < mrem) {
                    float v = acc[i][j][r];
                    v = v > 0.f ? v : 0.f;
                    latent[(size_t)(slot0 + row) * EXPERT_DIM + ccol_base + j * 16] = (_Float16)v;
                }
            }
        }
    }
}

// ---------------- Decode GEMM: out[tok] = prob[tok] * (latent[slot] @ dec[e]) + pre_b ----------------
__global__ __launch_bounds__(256) void decode_kernel(const _Float16* __restrict__ latent,
    const _Float16* __restrict__ decT, const int* __restrict__ order,
    const int* __restrict__ counts, const int* __restrict__ offsets,
    const float* __restrict__ prob, const float* __restrict__ pre_b,
    float* __restrict__ out)
{
    int e = blockIdx.z;
    int n_e = counts[e];
    int mt = blockIdx.y;
    if (mt * BM >= n_e) return;
    int nt = blockIdx.x;     // 0..5
    int slot0 = offsets[e] + mt * BM;
    int mrem = n_e - mt * BM;

    __shared__ _Float16 As[BM * BK];
    __shared__ _Float16 Bs[BN * BK];
    __shared__ int s_tok[BM];
    __shared__ float s_p[BM];

    int tid = threadIdx.x;
    if (tid < BM) {
        int tok = (tid < mrem) ? order[slot0 + tid] : 0;
        s_tok[tid] = tok;
        s_p[tid] = prob[tok];
    }

    const _Float16* Ae = latent + (size_t)slot0 * EXPERT_DIM;   // rows may run past mrem: latent is padded
    const _Float16* Be = decT + (size_t)e * EXPERT_DIM * D_IN + (size_t)(nt * BN) * EXPERT_DIM;

    int wave = tid >> 6, lane = tid & 63;
    int wm = wave >> 1, wn = wave & 1;

    int r0 = tid >> 2, sc = tid & 3;
    int c = (sc - (r0 >> 1)) & 3;
    const _Float16* paA0 = Ae + (size_t)r0 * EXPERT_DIM + c * 8;
    const _Float16* paA1 = Ae + (size_t)(r0 + 64) * EXPERT_DIM + c * 8;
    const _Float16* pb0 = Be + (size_t)r0 * EXPERT_DIM + c * 8;
    const _Float16* pb1 = Be + (size_t)(r0 + 64) * EXPERT_DIM + c * 8;
    _Float16* la0 = &As[(wave * 64) * 8];
    _Float16* la1 = &As[(wave * 64 + 256) * 8];
    _Float16* lb0 = &Bs[(wave * 64) * 8];
    _Float16* lb1 = &Bs[(wave * 64 + 256) * 8];

    int frag_off = ((((lane >> 4) + ((lane & 15) >> 1)) & 3) * 8);
    int mrow = lane & 15;

    floatx4 acc[4][4];
#pragma unroll
    for (int i = 0; i < 4; ++i)
#pragma unroll
        for (int j = 0; j < 4; ++j) acc[i][j] = (floatx4){0.f, 0.f, 0.f, 0.f};

#pragma unroll 1
    for (int k0 = 0; k0 < EXPERT_DIM; k0 += BK) {
        glds16(paA0 + k0, la0);
        glds16(paA1 + k0, la1);
        glds16(pb0 + k0, lb0);
        glds16(pb1 + k0, lb1);
        __syncthreads();

        half8 af[4], bf[4];
#pragma unroll
        for (int i = 0; i < 4; ++i) af[i] = *(const half8*)&As[(wm * 64 + i * 16 + mrow) * BK + frag_off];
#pragma unroll
        for (int i = 0; i < 4; ++i) bf[i] = *(const half8*)&Bs[(wn * 64 + i * 16 + mrow) * BK + frag_off];
#pragma unroll
        for (int i = 0; i < 4; ++i)
#pragma unroll
            for (int j = 0; j < 4; ++j)
                acc[i][j] = __builtin_amdgcn_mfma_f32_16x16x32_f16(af[i], bf[j], acc[i][j], 0, 0, 0);
        __syncthreads();
    }

    int crow_base = wm * 64 + (lane >> 4) * 4;
    int ccol_base = nt * BN + wn * 64 + (lane & 15);
#pragma unroll
    for (int i = 0; i < 4; ++i) {
#pragma unroll
        for (int j = 0; j < 4; ++j) {
            int col = ccol_base + j * 16;
            float pb = pre_b[col];
#pragma unroll
            for (int r = 0; r < 4; ++r) {
                int row = crow_base + i * 16 + r;
                if (row < mrem) {
                    out[(size_t)s_tok[row] * D_IN + col] = s_p[row] * acc[i][j][r] + pb;
                }
            }
        }
    }
}

extern "C" void kernel_launch(void* const* d_in, const int* in_sizes, int n_in,
                              void* d_out, int out_size, void* d_ws, size_t ws_size,
                              hipStream_t stream)
{
    const float* act      = (const float*)d_in[0];
    const float* pre_b    = (const float*)d_in[1];
    const float* enc      = (const float*)d_in[2];
    const float* dec      = (const float*)d_in[3];
    const float* router_b = (const float*)d_in[4];
    const float* router   = (const float*)d_in[5];
    float* out = (float*)d_out;

    char* w = (char*)d_ws;
    int* counts  = (int*)w;  w += 256;
    int* offsets = (int*)w;  w += 256;
    int* hist    = (int*)w;  w += ROUTER_BLOCKS * N_EXPERTS * 4;
    int* eidx    = (int*)w;  w += N_TOKENS * 4;
    int* lpos    = (int*)w;  w += N_TOKENS * 4;
    int* order   = (int*)w;  w += N_TOKENS * 4;
    float* prob  = (float*)w; w += N_TOKENS * 4;
    _Float16* encT   = (_Float16*)w; w += (size_t)N_EXPERTS * D_IN * EXPERT_DIM * 2;
    _Float16* decT   = (_Float16*)w; w += (size_t)N_EXPERTS * D_IN * EXPERT_DIM * 2;
    _Float16* latent = (_Float16*)w; w += (size_t)(N_TOKENS + BM) * EXPERT_DIM * 2;  // +BM pad rows for tail glds

    transpose_to_half<<<dim3(EXPERT_DIM / 64, D_IN / 64, N_EXPERTS), 256, 0, stream>>>(enc, encT, D_IN, EXPERT_DIM);
    transpose_to_half<<<dim3(D_IN / 64, EXPERT_DIM / 64, N_EXPERTS), 256, 0, stream>>>(dec, decT, EXPERT_DIM, D_IN);

    router_kernel<<<ROUTER_BLOCKS, 256, 0, stream>>>(act, router_b, router, prob, lpos, eidx, hist);
    scan_kernel<<<1, 256, 0, stream>>>(hist, counts, offsets);
    order_kernel<<<N_TOKENS / 256, 256, 0, stream>>>(eidx, lpos, hist, order);

    encode_kernel<<<dim3(EXPERT_DIM / BN, N_TOKENS / BM, N_EXPERTS), 256, 0, stream>>>(
        act, encT, order, counts, offsets, latent);
    decode_kernel<<<dim3(D_IN / BN, N_TOKENS / BM, N_EXPERTS), 256, 0, stream>>>(
        latent, decT, order, counts, offsets, prob, pre_b, out);
}

// Round 4
// 407.858 us; speedup vs baseline: 1.6557x; 1.0559x over previous
//
#include <hip/hip_runtime.h>
#include <hip/hip_bf16.h>
#include <hip/hip_fp16.h>

#define N_TOKENS 16384
#define D_IN 768
#define N_EXPERTS 8
#define EXPERT_DIM 2048

#define ROUTER_BLOCKS 256
#define TOK_PER_BLOCK 64

typedef _Float16 half8 __attribute__((ext_vector_type(8)));
typedef float floatx4 __attribute__((ext_vector_type(4)));

#define BM 128
#define BN 128
#define BK 32
// LDS tiles: UNPADDED 128x32 halves (64B rows), double-buffered.
// Swizzle: 16B chunk c of row r stored at chunk (c + (r>>1)) & 3 -> frag
// ds_read_b128 conflict-free (verified: SQ_LDS_BANK_CONFLICT == 0 in r3).

// s_waitcnt imm encodings (gfx9): vmcnt[3:0]|expcnt<<4|lgkmcnt<<8|vmcnt[5:4]<<14
#define WAIT_VM4 0xF74   // vmcnt(4), lgkm/exp unconstrained
#define WAIT_VM0 0xF70   // vmcnt(0)

__device__ __forceinline__ void glds16(const _Float16* g, _Float16* l) {
    __builtin_amdgcn_global_load_lds(
        (const __attribute__((address_space(1))) unsigned int*)g,
        (__attribute__((address_space(3))) unsigned int*)l, 16, 0, 0);
}

// ---------------- act fp32 -> f16 (one-time) ----------------
__global__ __launch_bounds__(256) void convert_act(const float* __restrict__ act,
    _Float16* __restrict__ act_h)
{
    size_t i = ((size_t)blockIdx.x * 256 + threadIdx.x) * 8;
    float4 v0 = *(const float4*)(act + i);
    float4 v1 = *(const float4*)(act + i + 4);
    half8 h;
    h[0] = (_Float16)v0.x; h[1] = (_Float16)v0.y; h[2] = (_Float16)v0.z; h[3] = (_Float16)v0.w;
    h[4] = (_Float16)v1.x; h[5] = (_Float16)v1.y; h[6] = (_Float16)v1.z; h[7] = (_Float16)v1.w;
    *(half8*)(act_h + i) = h;
}

// ---------------- Phase 1: router (fp32: argmax is a decision, keep exact) ----------------
__global__ __launch_bounds__(256) void router_kernel(const float* __restrict__ act,
    const float* __restrict__ router_b, const float* __restrict__ router,
    float* __restrict__ prob, int* __restrict__ localpos, int* __restrict__ eidx,
    int* __restrict__ hist)
{
    __shared__ int h[N_EXPERTS];
    if (threadIdx.x < N_EXPERTS) h[threadIdx.x] = 0;
    __syncthreads();

    int wave = threadIdx.x >> 6, lane = threadIdx.x & 63;
#pragma unroll 1
    for (int it = 0; it < 16; ++it) {
        int t = blockIdx.x * TOK_PER_BLOCK + wave * 16 + it;
        float acc[8];
#pragma unroll
        for (int e = 0; e < 8; ++e) acc[e] = 0.f;
        const float* arow = act + (size_t)t * D_IN;
#pragma unroll
        for (int i0 = 0; i0 < D_IN; i0 += 64) {
            int i = i0 + lane;
            float a = arow[i] - router_b[i];
            const float* r = router + i * 8;
#pragma unroll
            for (int e = 0; e < 8; ++e) acc[e] += a * r[e];
        }
#pragma unroll
        for (int s = 32; s > 0; s >>= 1) {
#pragma unroll
            for (int e = 0; e < 8; ++e) acc[e] += __shfl_down(acc[e], s, 64);
        }
        if (lane == 0) {
            float m = acc[0]; int ai = 0;
#pragma unroll
            for (int e = 1; e < 8; ++e) if (acc[e] > m) { m = acc[e]; ai = e; }
            float s = 0.f;
#pragma unroll
            for (int e = 0; e < 8; ++e) s += __expf(acc[e] - m);
            prob[t] = 1.0f / s;
            eidx[t] = ai;
            localpos[t] = atomicAdd(&h[ai], 1);
        }
    }
    __syncthreads();
    if (threadIdx.x < N_EXPERTS) hist[blockIdx.x * N_EXPERTS + threadIdx.x] = h[threadIdx.x];
}

// ---------------- Phase 2: scan ----------------
__global__ __launch_bounds__(256) void scan_kernel(int* __restrict__ hist,
    int* __restrict__ counts, int* __restrict__ offsets)
{
    __shared__ int sh[ROUTER_BLOCKS * N_EXPERTS];
    __shared__ int tot[N_EXPERTS], off[N_EXPERTS];
    int tid = threadIdx.x;
    *(int4*)&sh[tid * 8]     = *(const int4*)&hist[tid * 8];
    *(int4*)&sh[tid * 8 + 4] = *(const int4*)&hist[tid * 8 + 4];
    __syncthreads();
    if (tid < N_EXPERTS) {
        int run = 0;
        for (int b = 0; b < ROUTER_BLOCKS; ++b) {
            int v = sh[b * 8 + tid];
            sh[b * 8 + tid] = run;
            run += v;
        }
        tot[tid] = run;
    }
    __syncthreads();
    if (tid == 0) {
        int run = 0;
        for (int e = 0; e < N_EXPERTS; ++e) {
            off[e] = run; offsets[e] = run; counts[e] = tot[e]; run += tot[e];
        }
    }
    __syncthreads();
    int4 a = *(const int4*)&sh[tid * 8];
    int4 b = *(const int4*)&sh[tid * 8 + 4];
    a.x += off[0]; a.y += off[1]; a.z += off[2]; a.w += off[3];
    b.x += off[4]; b.y += off[5]; b.z += off[6]; b.w += off[7];
    *(int4*)&hist[tid * 8]     = a;
    *(int4*)&hist[tid * 8 + 4] = b;
}

// ---------------- Phase 3: scatter ----------------
__global__ __launch_bounds__(256) void order_kernel(const int* __restrict__ eidx,
    const int* __restrict__ localpos, const int* __restrict__ hist,
    int* __restrict__ order)
{
    int t = blockIdx.x * 256 + threadIdx.x;
    int base = hist[(t >> 6) * N_EXPERTS + eidx[t]];
    order[base + localpos[t]] = t;
}

// ---------------- Weight transpose fp32 [E][K][Nc] -> f16 [E][Nc][K] ----------------
__global__ __launch_bounds__(256) void transpose_to_half(const float* __restrict__ W,
    _Float16* __restrict__ WT, int K, int Nc)
{
    __shared__ _Float16 tile[64][72];
    size_t esz = (size_t)K * Nc;
    const float* We = W + (size_t)blockIdx.z * esz;
    _Float16* WTe = WT + (size_t)blockIdx.z * esz;
    int n0 = blockIdx.x * 64, k0 = blockIdx.y * 64;
    int tr = threadIdx.x >> 4;
    int tc = threadIdx.x & 15;
#pragma unroll
    for (int rr = 0; rr < 64; rr += 16) {
        int k = k0 + rr + tr;
        float4 v = *(const float4*)(We + (size_t)k * Nc + n0 + tc * 4);
        tile[tc * 4 + 0][rr + tr] = (_Float16)v.x;
        tile[tc * 4 + 1][rr + tr] = (_Float16)v.y;
        tile[tc * 4 + 2][rr + tr] = (_Float16)v.z;
        tile[tc * 4 + 3][rr + tr] = (_Float16)v.w;
    }
    __syncthreads();
#pragma unroll
    for (int p = 0; p < 2; ++p) {
        int id = threadIdx.x + p * 256;
        int r = id >> 3, ch = id & 7;
        half8 v = *(const half8*)&tile[r][ch * 8];
        *(half8*)(WTe + (size_t)(n0 + r) * K + k0 + ch * 8) = v;
    }
}

// ---------------- Encode GEMM (pure-glds, double-buffered, raw barriers) ----------------
__global__ __launch_bounds__(256) void encode_kernel(const _Float16* __restrict__ act_h,
    const _Float16* __restrict__ encT, const int* __restrict__ order,
    const int* __restrict__ counts, const int* __restrict__ offsets,
    _Float16* __restrict__ latent)
{
    int e = blockIdx.z;
    int n_e = counts[e];
    int mt = blockIdx.y;
    if (mt * BM >= n_e) return;
    int nt = blockIdx.x;
    int slot0 = offsets[e] + mt * BM;
    int mrem = n_e - mt * BM;

    __shared__ _Float16 As[2][BM * BK];
    __shared__ _Float16 Bs[2][BN * BK];
    __shared__ int s_tok[BM];

    int tid = threadIdx.x;
    if (tid < BM) s_tok[tid] = (tid < mrem) ? order[slot0 + tid] : 0;  // clamp: garbage rows discarded at store
    __syncthreads();

    int wave = tid >> 6, lane = tid & 63;
    int wm = wave >> 1, wn = wave & 1;

    // staging geometry: chunk id = wave*64 + lane (+256 for second half)
    int r_lo = wave * 16 + (lane >> 2);          // row 0..63
    int sc = lane & 3;
    int c = (sc - (r_lo >> 1)) & 3;              // same for r_lo and r_lo+64 (+32 rows == 0 mod 4 after >>1)
    const _Float16* Be = encT + (size_t)e * D_IN * EXPERT_DIM + (size_t)(nt * BN) * D_IN;
    const _Float16* pa0 = act_h + (size_t)s_tok[r_lo] * D_IN + c * 8;
    const _Float16* pa1 = act_h + (size_t)s_tok[r_lo + 64] * D_IN + c * 8;
    const _Float16* pb0 = Be + (size_t)r_lo * D_IN + c * 8;
    const _Float16* pb1 = Be + (size_t)(r_lo + 64) * D_IN + c * 8;

    int frag_off = ((((lane >> 4) + ((lane & 15) >> 1)) & 3) * 8);
    int mrow = lane & 15;

    floatx4 acc[4][4];
#pragma unroll
    for (int i = 0; i < 4; ++i)
#pragma unroll
        for (int j = 0; j < 4; ++j) acc[i][j] = (floatx4){0.f, 0.f, 0.f, 0.f};

#define ENC_ISSUE(kk, buf)                                            \
    do {                                                              \
        int k0_ = (kk) * BK;                                          \
        glds16(pa0 + k0_, &As[buf][(wave * 64) * 8]);                 \
        glds16(pa1 + k0_, &As[buf][(256 + wave * 64) * 8]);           \
        glds16(pb0 + k0_, &Bs[buf][(wave * 64) * 8]);                 \
        glds16(pb1 + k0_, &Bs[buf][(256 + wave * 64) * 8]);           \
    } while (0)

    const int NT = D_IN / BK;   // 24
    ENC_ISSUE(0, 0);
#pragma unroll 1
    for (int k = 0; k < NT; ++k) {
        if (k + 1 < NT) {
            ENC_ISSUE(k + 1, (k + 1) & 1);
            __builtin_amdgcn_s_waitcnt(WAIT_VM4);   // tile k done; k+1 stays in flight
        } else {
            __builtin_amdgcn_s_waitcnt(WAIT_VM0);
        }
        __builtin_amdgcn_s_barrier();
        int b = k & 1;
        half8 af[4], bf[4];
#pragma unroll
        for (int i = 0; i < 4; ++i) af[i] = *(const half8*)&As[b][(wm * 64 + i * 16 + mrow) * BK + frag_off];
#pragma unroll
        for (int i = 0; i < 4; ++i) bf[i] = *(const half8*)&Bs[b][(wn * 64 + i * 16 + mrow) * BK + frag_off];
#pragma unroll
        for (int i = 0; i < 4; ++i)
#pragma unroll
            for (int j = 0; j < 4; ++j)
                acc[i][j] = __builtin_amdgcn_mfma_f32_16x16x32_f16(af[i], bf[j], acc[i][j], 0, 0, 0);
        __builtin_amdgcn_s_barrier();   // protect buf b before tile k+2 overwrites it
    }
#undef ENC_ISSUE

    int crow_base = wm * 64 + (lane >> 4) * 4;
    int ccol_base = nt * BN + wn * 64 + (lane & 15);
#pragma unroll
    for (int i = 0; i < 4; ++i) {
#pragma unroll
        for (int j = 0; j < 4; ++j) {
#pragma unroll
            for (int r = 0; r < 4; ++r) {
                int row = crow_base + i * 16 + r;
                if (row < mrem) {
                    float v = acc[i][j][r];
                    v = v > 0.f ? v : 0.f;
                    latent[(size_t)(slot0 + row) * EXPERT_DIM + ccol_base + j * 16] = (_Float16)v;
                }
            }
        }
    }
}

// ---------------- Decode GEMM (pure-glds, double-buffered, raw barriers) ----------------
__global__ __launch_bounds__(256) void decode_kernel(const _Float16* __restrict__ latent,
    const _Float16* __restrict__ decT, const int* __restrict__ order,
    const int* __restrict__ counts, const int* __restrict__ offsets,
    const float* __restrict__ prob, const float* __restrict__ pre_b,
    float* __restrict__ out)
{
    int e = blockIdx.z;
    int n_e = counts[e];
    int mt = blockIdx.y;
    if (mt * BM >= n_e) return;
    int nt = blockIdx.x;
    int slot0 = offsets[e] + mt * BM;
    int mrem = n_e - mt * BM;

    __shared__ _Float16 As[2][BM * BK];
    __shared__ _Float16 Bs[2][BN * BK];
    __shared__ int s_tok[BM];
    __shared__ float s_p[BM];

    int tid = threadIdx.x;
    if (tid < BM) {
        int tok = (tid < mrem) ? order[slot0 + tid] : 0;
        s_tok[tid] = tok;
        s_p[tid] = prob[tok];
    }
    // no sync needed here: loop barriers order these writes before the epilogue reads

    const _Float16* Ae = latent + (size_t)slot0 * EXPERT_DIM;   // latent padded by BM rows
    const _Float16* Be = decT + (size_t)e * EXPERT_DIM * D_IN + (size_t)(nt * BN) * EXPERT_DIM;

    int wave = tid >> 6, lane = tid & 63;
    int wm = wave >> 1, wn = wave & 1;

    int r_lo = wave * 16 + (lane >> 2);
    int sc = lane & 3;
    int c = (sc - (r_lo >> 1)) & 3;
    const _Float16* pa0 = Ae + (size_t)r_lo * EXPERT_DIM + c * 8;
    const _Float16* pa1 = Ae + (size_t)(r_lo + 64) * EXPERT_DIM + c * 8;
    const _Float16* pb0 = Be + (size_t)r_lo * EXPERT_DIM + c * 8;
    const _Float16* pb1 = Be + (size_t)(r_lo + 64) * EXPERT_DIM + c * 8;

    int frag_off = ((((lane >> 4) + ((lane & 15) >> 1)) & 3) * 8);
    int mrow = lane & 15;

    floatx4 acc[4][4];
#pragma unroll
    for (int i = 0; i < 4; ++i)
#pragma unroll
        for (int j = 0; j < 4; ++j) acc[i][j] = (floatx4){0.f, 0.f, 0.f, 0.f};

#define DEC_ISSUE(kk, buf)                                            \
    do {                                                              \
        int k0_ = (kk) * BK;                                          \
        glds16(pa0 + k0_, &As[buf][(wave * 64) * 8]);                 \
        glds16(pa1 + k0_, &As[buf][(256 + wave * 64) * 8]);           \
        glds16(pb0 + k0_, &Bs[buf][(wave * 64) * 8]);                 \
        glds16(pb1 + k0_, &Bs[buf][(256 + wave * 64) * 8]);           \
    } while (0)

    const int NT = EXPERT_DIM / BK;   // 64
    DEC_ISSUE(0, 0);
#pragma unroll 1
    for (int k = 0; k < NT; ++k) {
        if (k + 1 < NT) {
            DEC_ISSUE(k + 1, (k + 1) & 1);
            __builtin_amdgcn_s_waitcnt(WAIT_VM4);
        } else {
            __builtin_amdgcn_s_waitcnt(WAIT_VM0);
        }
        __builtin_amdgcn_s_barrier();
        int b = k & 1;
        half8 af[4], bf[4];
#pragma unroll
        for (int i = 0; i < 4; ++i) af[i] = *(const half8*)&As[b][(wm * 64 + i * 16 + mrow) * BK + frag_off];
#pragma unroll
        for (int i = 0; i < 4; ++i) bf[i] = *(const half8*)&Bs[b][(wn * 64 + i * 16 + mrow) * BK + frag_off];
#pragma unroll
        for (int i = 0; i < 4; ++i)
#pragma unroll
            for (int j = 0; j < 4; ++j)
                acc[i][j] = __builtin_amdgcn_mfma_f32_16x16x32_f16(af[i], bf[j], acc[i][j], 0, 0, 0);
        __builtin_amdgcn_s_barrier();
    }
#undef DEC_ISSUE

    int crow_base = wm * 64 + (lane >> 4) * 4;
    int ccol_base = nt * BN + wn * 64 + (lane & 15);
#pragma unroll
    for (int i = 0; i < 4; ++i) {
#pragma unroll
        for (int j = 0; j < 4; ++j) {
            int col = ccol_base + j * 16;
            float pb = pre_b[col];
#pragma unroll
            for (int r = 0; r < 4; ++r) {
                int row = crow_base + i * 16 + r;
                if (row < mrem) {
                    out[(size_t)s_tok[row] * D_IN + col] = s_p[row] * acc[i][j][r] + pb;
                }
            }
        }
    }
}

extern "C" void kernel_launch(void* const* d_in, const int* in_sizes, int n_in,
                              void* d_out, int out_size, void* d_ws, size_t ws_size,
                              hipStream_t stream)
{
    const float* act      = (const float*)d_in[0];
    const float* pre_b    = (const float*)d_in[1];
    const float* enc      = (const float*)d_in[2];
    const float* dec      = (const float*)d_in[3];
    const float* router_b = (const float*)d_in[4];
    const float* router   = (const float*)d_in[5];
    float* out = (float*)d_out;

    char* w = (char*)d_ws;
    int* counts  = (int*)w;  w += 256;
    int* offsets = (int*)w;  w += 256;
    int* hist    = (int*)w;  w += ROUTER_BLOCKS * N_EXPERTS * 4;
    int* eidx    = (int*)w;  w += N_TOKENS * 4;
    int* lpos    = (int*)w;  w += N_TOKENS * 4;
    int* order   = (int*)w;  w += N_TOKENS * 4;
    float* prob  = (float*)w; w += N_TOKENS * 4;
    _Float16* act_h  = (_Float16*)w; w += (size_t)N_TOKENS * D_IN * 2;
    _Float16* encT   = (_Float16*)w; w += (size_t)N_EXPERTS * D_IN * EXPERT_DIM * 2;
    _Float16* decT   = (_Float16*)w; w += (size_t)N_EXPERTS * D_IN * EXPERT_DIM * 2;
    _Float16* latent = (_Float16*)w; w += (size_t)(N_TOKENS + BM) * EXPERT_DIM * 2;

    router_kernel<<<ROUTER_BLOCKS, 256, 0, stream>>>(act, router_b, router, prob, lpos, eidx, hist);
    scan_kernel<<<1, 256, 0, stream>>>(hist, counts, offsets);
    order_kernel<<<N_TOKENS / 256, 256, 0, stream>>>(eidx, lpos, hist, order);

    convert_act<<<N_TOKENS * D_IN / (256 * 8), 256, 0, stream>>>(act, act_h);
    transpose_to_half<<<dim3(EXPERT_DIM / 64, D_IN / 64, N_EXPERTS), 256, 0, stream>>>(enc, encT, D_IN, EXPERT_DIM);
    transpose_to_half<<<dim3(D_IN / 64, EXPERT_DIM / 64, N_EXPERTS), 256, 0, stream>>>(dec, decT, EXPERT_DIM, D_IN);

    encode_kernel<<<dim3(EXPERT_DIM / BN, N_TOKENS / BM, N_EXPERTS), 256, 0, stream>>>(
        act_h, encT, order, counts, offsets, latent);
    decode_kernel<<<dim3(D_IN / BN, N_TOKENS / BM, N_EXPERTS), 256, 0, stream>>>(
        latent, decT, order, counts, offsets, prob, pre_b, out);
}

// Round 5
// 403.791 us; speedup vs baseline: 1.6724x; 1.0101x over previous
//
#include <hip/hip_runtime.h>
#include <hip/hip_bf16.h>
#include <hip/hip_fp16.h>

#define N_TOKENS 16384
#define D_IN 768
#define N_EXPERTS 8
#define EXPERT_DIM 2048

#define ROUTER_BLOCKS 256
#define TOK_PER_BLOCK 64

typedef _Float16 half8 __attribute__((ext_vector_type(8)));
typedef float floatx4 __attribute__((ext_vector_type(4)));

#define BM 128
#define BN 128
#define BK 32
#define NBUF 3
// LDS tiles: UNPADDED 128x32 halves (64B rows), triple-buffered (prefetch depth 2).
// Swizzle: 16B chunk c of row r stored at chunk (c + (r>>1)) & 3 -> frag
// ds_read_b128 conflict-free (verified: SQ_LDS_BANK_CONFLICT == 0 in r3/r4).

// s_waitcnt imm (gfx9): vmcnt[3:0] | expcnt<<4 | lgkmcnt<<8 | vmcnt[5:4]<<14
#define WAIT_VM8 0xF78   // vmcnt(8)  : tiles k+1,k+2 in flight, tile k landed
#define WAIT_VM4 0xF74   // vmcnt(4)
#define WAIT_VM0 0xF70   // vmcnt(0)

__device__ __forceinline__ void glds16(const _Float16* g, _Float16* l) {
    __builtin_amdgcn_global_load_lds(
        (const __attribute__((address_space(1))) unsigned int*)g,
        (__attribute__((address_space(3))) unsigned int*)l, 16, 0, 0);
}

// ---------------- act fp32 -> f16 (one-time) ----------------
__global__ __launch_bounds__(256) void convert_act(const float* __restrict__ act,
    _Float16* __restrict__ act_h)
{
    size_t i = ((size_t)blockIdx.x * 256 + threadIdx.x) * 8;
    float4 v0 = *(const float4*)(act + i);
    float4 v1 = *(const float4*)(act + i + 4);
    half8 h;
    h[0] = (_Float16)v0.x; h[1] = (_Float16)v0.y; h[2] = (_Float16)v0.z; h[3] = (_Float16)v0.w;
    h[4] = (_Float16)v1.x; h[5] = (_Float16)v1.y; h[6] = (_Float16)v1.z; h[7] = (_Float16)v1.w;
    *(half8*)(act_h + i) = h;
}

// ---------------- Phase 1: router (fp32: argmax is a decision, keep exact) ----------------
__global__ __launch_bounds__(256) void router_kernel(const float* __restrict__ act,
    const float* __restrict__ router_b, const float* __restrict__ router,
    float* __restrict__ prob, int* __restrict__ localpos, int* __restrict__ eidx,
    int* __restrict__ hist)
{
    __shared__ int h[N_EXPERTS];
    if (threadIdx.x < N_EXPERTS) h[threadIdx.x] = 0;
    __syncthreads();

    int wave = threadIdx.x >> 6, lane = threadIdx.x & 63;
#pragma unroll 1
    for (int it = 0; it < 16; ++it) {
        int t = blockIdx.x * TOK_PER_BLOCK + wave * 16 + it;
        float acc[8];
#pragma unroll
        for (int e = 0; e < 8; ++e) acc[e] = 0.f;
        const float* arow = act + (size_t)t * D_IN;
#pragma unroll
        for (int i0 = 0; i0 < D_IN; i0 += 64) {
            int i = i0 + lane;
            float a = arow[i] - router_b[i];
            const float* r = router + i * 8;
#pragma unroll
            for (int e = 0; e < 8; ++e) acc[e] += a * r[e];
        }
#pragma unroll
        for (int s = 32; s > 0; s >>= 1) {
#pragma unroll
            for (int e = 0; e < 8; ++e) acc[e] += __shfl_down(acc[e], s, 64);
        }
        if (lane == 0) {
            float m = acc[0]; int ai = 0;
#pragma unroll
            for (int e = 1; e < 8; ++e) if (acc[e] > m) { m = acc[e]; ai = e; }
            float s = 0.f;
#pragma unroll
            for (int e = 0; e < 8; ++e) s += __expf(acc[e] - m);
            prob[t] = 1.0f / s;
            eidx[t] = ai;
            localpos[t] = atomicAdd(&h[ai], 1);
        }
    }
    __syncthreads();
    if (threadIdx.x < N_EXPERTS) hist[blockIdx.x * N_EXPERTS + threadIdx.x] = h[threadIdx.x];
}

// ---------------- Phase 2: scan ----------------
__global__ __launch_bounds__(256) void scan_kernel(int* __restrict__ hist,
    int* __restrict__ counts, int* __restrict__ offsets)
{
    __shared__ int sh[ROUTER_BLOCKS * N_EXPERTS];
    __shared__ int tot[N_EXPERTS], off[N_EXPERTS];
    int tid = threadIdx.x;
    *(int4*)&sh[tid * 8]     = *(const int4*)&hist[tid * 8];
    *(int4*)&sh[tid * 8 + 4] = *(const int4*)&hist[tid * 8 + 4];
    __syncthreads();
    if (tid < N_EXPERTS) {
        int run = 0;
        for (int b = 0; b < ROUTER_BLOCKS; ++b) {
            int v = sh[b * 8 + tid];
            sh[b * 8 + tid] = run;
            run += v;
        }
        tot[tid] = run;
    }
    __syncthreads();
    if (tid == 0) {
        int run = 0;
        for (int e = 0; e < N_EXPERTS; ++e) {
            off[e] = run; offsets[e] = run; counts[e] = tot[e]; run += tot[e];
        }
    }
    __syncthreads();
    int4 a = *(const int4*)&sh[tid * 8];
    int4 b = *(const int4*)&sh[tid * 8 + 4];
    a.x += off[0]; a.y += off[1]; a.z += off[2]; a.w += off[3];
    b.x += off[4]; b.y += off[5]; b.z += off[6]; b.w += off[7];
    *(int4*)&hist[tid * 8]     = a;
    *(int4*)&hist[tid * 8 + 4] = b;
}

// ---------------- Phase 3: scatter ----------------
__global__ __launch_bounds__(256) void order_kernel(const int* __restrict__ eidx,
    const int* __restrict__ localpos, const int* __restrict__ hist,
    int* __restrict__ order)
{
    int t = blockIdx.x * 256 + threadIdx.x;
    int base = hist[(t >> 6) * N_EXPERTS + eidx[t]];
    order[base + localpos[t]] = t;
}

// ---------------- Weight transpose fp32 [E][K][Nc] -> f16 [E][Nc][K] ----------------
__global__ __launch_bounds__(256) void transpose_to_half(const float* __restrict__ W,
    _Float16* __restrict__ WT, int K, int Nc)
{
    __shared__ _Float16 tile[64][72];
    size_t esz = (size_t)K * Nc;
    const float* We = W + (size_t)blockIdx.z * esz;
    _Float16* WTe = WT + (size_t)blockIdx.z * esz;
    int n0 = blockIdx.x * 64, k0 = blockIdx.y * 64;
    int tr = threadIdx.x >> 4;
    int tc = threadIdx.x & 15;
#pragma unroll
    for (int rr = 0; rr < 64; rr += 16) {
        int k = k0 + rr + tr;
        float4 v = *(const float4*)(We + (size_t)k * Nc + n0 + tc * 4);
        tile[tc * 4 + 0][rr + tr] = (_Float16)v.x;
        tile[tc * 4 + 1][rr + tr] = (_Float16)v.y;
        tile[tc * 4 + 2][rr + tr] = (_Float16)v.z;
        tile[tc * 4 + 3][rr + tr] = (_Float16)v.w;
    }
    __syncthreads();
#pragma unroll
    for (int p = 0; p < 2; ++p) {
        int id = threadIdx.x + p * 256;
        int r = id >> 3, ch = id & 7;
        half8 v = *(const half8*)&tile[r][ch * 8];
        *(half8*)(WTe + (size_t)(n0 + r) * K + k0 + ch * 8) = v;
    }
}

// ---------------- Encode GEMM (triple-buffered, depth-2 prefetch, XCD swizzle) ----------------
// 1D grid 16384: xcd = id&7, r = id>>3; group_within = r>>7 (16), mt = r&127;
// P = xcd + 8*group_within in [0,128): e = P>>4, nt = P&15.
// All mt-blocks of one (e,nt) land on one XCD -> B tile (196KB) L2-resident.
__global__ __launch_bounds__(256) void encode_kernel(const _Float16* __restrict__ act_h,
    const _Float16* __restrict__ encT, const int* __restrict__ order,
    const int* __restrict__ counts, const int* __restrict__ offsets,
    _Float16* __restrict__ latent)
{
    int id = blockIdx.x;
    int P = (id & 7) + 8 * ((id >> 3) >> 7);
    int mt = (id >> 3) & 127;
    int e = P >> 4, nt = P & 15;

    int n_e = counts[e];
    if (mt * BM >= n_e) return;
    int slot0 = offsets[e] + mt * BM;
    int mrem = n_e - mt * BM;

    __shared__ _Float16 As[NBUF][BM * BK];
    __shared__ _Float16 Bs[NBUF][BN * BK];
    __shared__ int s_tok[BM];

    int tid = threadIdx.x;
    if (tid < BM) s_tok[tid] = (tid < mrem) ? order[slot0 + tid] : 0;  // clamp: garbage rows dropped at store
    __syncthreads();

    int wave = tid >> 6, lane = tid & 63;
    int wm = wave >> 1, wn = wave & 1;

    int r_lo = wave * 16 + (lane >> 2);          // row 0..63
    int sc = lane & 3;
    int c = (sc - (r_lo >> 1)) & 3;
    const _Float16* Be = encT + (size_t)e * D_IN * EXPERT_DIM + (size_t)(nt * BN) * D_IN;
    const _Float16* pa0 = act_h + (size_t)s_tok[r_lo] * D_IN + c * 8;
    const _Float16* pa1 = act_h + (size_t)s_tok[r_lo + 64] * D_IN + c * 8;
    const _Float16* pb0 = Be + (size_t)r_lo * D_IN + c * 8;
    const _Float16* pb1 = Be + (size_t)(r_lo + 64) * D_IN + c * 8;

    int frag_off = ((((lane >> 4) + ((lane & 15) >> 1)) & 3) * 8);
    int mrow = lane & 15;

    floatx4 acc[4][4];
#pragma unroll
    for (int i = 0; i < 4; ++i)
#pragma unroll
        for (int j = 0; j < 4; ++j) acc[i][j] = (floatx4){0.f, 0.f, 0.f, 0.f};

#define ENC_ISSUE(kk, buf)                                            \
    do {                                                              \
        int k0_ = (kk) * BK;                                          \
        glds16(pa0 + k0_, &As[buf][(wave * 64) * 8]);                 \
        glds16(pa1 + k0_, &As[buf][(256 + wave * 64) * 8]);           \
        glds16(pb0 + k0_, &Bs[buf][(wave * 64) * 8]);                 \
        glds16(pb1 + k0_, &Bs[buf][(256 + wave * 64) * 8]);           \
    } while (0)

    const int NT = D_IN / BK;   // 24
    ENC_ISSUE(0, 0);
    ENC_ISSUE(1, 1);
    int buf = 0, nxt = 2;
#pragma unroll 1
    for (int k = 0; k < NT; ++k) {
        if (k + 2 < NT) {
            ENC_ISSUE(k + 2, nxt);
            __builtin_amdgcn_s_waitcnt(WAIT_VM8);   // tile k landed; k+1,k+2 in flight
        } else if (k + 1 < NT) {
            __builtin_amdgcn_s_waitcnt(WAIT_VM4);
        } else {
            __builtin_amdgcn_s_waitcnt(WAIT_VM0);
        }
        __builtin_amdgcn_s_barrier();
        half8 af[4], bf[4];
#pragma unroll
        for (int i = 0; i < 4; ++i) af[i] = *(const half8*)&As[buf][(wm * 64 + i * 16 + mrow) * BK + frag_off];
#pragma unroll
        for (int i = 0; i < 4; ++i) bf[i] = *(const half8*)&Bs[buf][(wn * 64 + i * 16 + mrow) * BK + frag_off];
#pragma unroll
        for (int i = 0; i < 4; ++i)
#pragma unroll
            for (int j = 0; j < 4; ++j)
                acc[i][j] = __builtin_amdgcn_mfma_f32_16x16x32_f16(af[i], bf[j], acc[i][j], 0, 0, 0);
        __builtin_amdgcn_s_barrier();   // all waves done reading buf before its reuse as k+3's target
        buf = (buf == NBUF - 1) ? 0 : buf + 1;
        nxt = (nxt == NBUF - 1) ? 0 : nxt + 1;
    }
#undef ENC_ISSUE

    int crow_base = wm * 64 + (lane >> 4) * 4;
    int ccol_base = nt * BN + wn * 64 + (lane & 15);
#pragma unroll
    for (int i = 0; i < 4; ++i) {
#pragma unroll
        for (int j = 0; j < 4; ++j) {
#pragma unroll
            for (int r = 0; r < 4; ++r) {
                int row = crow_base + i * 16 + r;
                if (row < mrem) {
                    float v = acc[i][j][r];
                    v = v > 0.f ? v : 0.f;
                    latent[(size_t)(slot0 + row) * EXPERT_DIM + ccol_base + j * 16] = (_Float16)v;
                }
            }
        }
    }
}

// ---------------- Decode GEMM (triple-buffered, depth-2 prefetch, XCD swizzle) ----------------
// 1D grid 6144: xcd = id&7, r = id>>3 (768); group_within = r/128 (6), mt = r&127;
// P = xcd + 8*group_within in [0,48): e = P/6, nt = P%6.
__global__ __launch_bounds__(256) void decode_kernel(const _Float16* __restrict__ latent,
    const _Float16* __restrict__ decT, const int* __restrict__ order,
    const int* __restrict__ counts, const int* __restrict__ offsets,
    const float* __restrict__ prob, const float* __restrict__ pre_b,
    float* __restrict__ out)
{
    int id = blockIdx.x;
    int P = (id & 7) + 8 * ((id >> 3) >> 7);
    int mt = (id >> 3) & 127;
    int e = P / 6, nt = P - e * 6;

    int n_e = counts[e];
    if (mt * BM >= n_e) return;
    int slot0 = offsets[e] + mt * BM;
    int mrem = n_e - mt * BM;

    __shared__ _Float16 As[NBUF][BM * BK];
    __shared__ _Float16 Bs[NBUF][BN * BK];
    __shared__ int s_tok[BM];
    __shared__ float s_p[BM];

    int tid = threadIdx.x;
    if (tid < BM) {
        int tok = (tid < mrem) ? order[slot0 + tid] : 0;
        s_tok[tid] = tok;
        s_p[tid] = prob[tok];
    }
    __syncthreads();

    const _Float16* Ae = latent + (size_t)slot0 * EXPERT_DIM;   // latent padded by BM rows
    const _Float16* Be = decT + (size_t)e * EXPERT_DIM * D_IN + (size_t)(nt * BN) * EXPERT_DIM;

    int wave = tid >> 6, lane = tid & 63;
    int wm = wave >> 1, wn = wave & 1;

    int r_lo = wave * 16 + (lane >> 2);
    int sc = lane & 3;
    int c = (sc - (r_lo >> 1)) & 3;
    const _Float16* pa0 = Ae + (size_t)r_lo * EXPERT_DIM + c * 8;
    const _Float16* pa1 = Ae + (size_t)(r_lo + 64) * EXPERT_DIM + c * 8;
    const _Float16* pb0 = Be + (size_t)r_lo * EXPERT_DIM + c * 8;
    const _Float16* pb1 = Be + (size_t)(r_lo + 64) * EXPERT_DIM + c * 8;

    int frag_off = ((((lane >> 4) + ((lane & 15) >> 1)) & 3) * 8);
    int mrow = lane & 15;

    floatx4 acc[4][4];
#pragma unroll
    for (int i = 0; i < 4; ++i)
#pragma unroll
        for (int j = 0; j < 4; ++j) acc[i][j] = (floatx4){0.f, 0.f, 0.f, 0.f};

#define DEC_ISSUE(kk, buf)                                            \
    do {                                                              \
        int k0_ = (kk) * BK;                                          \
        glds16(pa0 + k0_, &As[buf][(wave * 64) * 8]);                 \
        glds16(pa1 + k0_, &As[buf][(256 + wave * 64) * 8]);           \
        glds16(pb0 + k0_, &Bs[buf][(wave * 64) * 8]);                 \
        glds16(pb1 + k0_, &Bs[buf][(256 + wave * 64) * 8]);           \
    } while (0)

    const int NT = EXPERT_DIM / BK;   // 64
    DEC_ISSUE(0, 0);
    DEC_ISSUE(1, 1);
    int buf = 0, nxt = 2;
#pragma unroll 1
    for (int k = 0; k < NT; ++k) {
        if (k + 2 < NT) {
            DEC_ISSUE(k + 2, nxt);
            __builtin_amdgcn_s_waitcnt(WAIT_VM8);
        } else if (k + 1 < NT) {
            __builtin_amdgcn_s_waitcnt(WAIT_VM4);
        } else {
            __builtin_amdgcn_s_waitcnt(WAIT_VM0);
        }
        __builtin_amdgcn_s_barrier();
        half8 af[4], bf[4];
#pragma unroll
        for (int i = 0; i < 4; ++i) af[i] = *(const half8*)&As[buf][(wm * 64 + i * 16 + mrow) * BK + frag_off];
#pragma unroll
        for (int i = 0; i < 4; ++i) bf[i] = *(const half8*)&Bs[buf][(wn * 64 + i * 16 + mrow) * BK + frag_off];
#pragma unroll
        for (int i = 0; i < 4; ++i)
#pragma unroll
            for (int j = 0; j < 4; ++j)
                acc[i][j] = __builtin_amdgcn_mfma_f32_16x16x32_f16(af[i], bf[j], acc[i][j], 0, 0, 0);
        __builtin_amdgcn_s_barrier();
        buf = (buf == NBUF - 1) ? 0 : buf + 1;
        nxt = (nxt == NBUF - 1) ? 0 : nxt + 1;
    }
#undef DEC_ISSUE

    int crow_base = wm * 64 + (lane >> 4) * 4;
    int ccol_base = nt * BN + wn * 64 + (lane & 15);
#pragma unroll
    for (int i = 0; i < 4; ++i) {
#pragma unroll
        for (int j = 0; j < 4; ++j) {
            int col = ccol_base + j * 16;
            float pb = pre_b[col];
#pragma unroll
            for (int r = 0; r < 4; ++r) {
                int row = crow_base + i * 16 + r;
                if (row < mrem) {
                    out[(size_t)s_tok[row] * D_IN + col] = s_p[row] * acc[i][j][r] + pb;
                }
            }
        }
    }
}

extern "C" void kernel_launch(void* const* d_in, const int* in_sizes, int n_in,
                              void* d_out, int out_size, void* d_ws, size_t ws_size,
                              hipStream_t stream)
{
    const float* act      = (const float*)d_in[0];
    const float* pre_b    = (const float*)d_in[1];
    const float* enc      = (const float*)d_in[2];
    const float* dec      = (const float*)d_in[3];
    const float* router_b = (const float*)d_in[4];
    const float* router   = (const float*)d_in[5];
    float* out = (float*)d_out;

    char* w = (char*)d_ws;
    int* counts  = (int*)w;  w += 256;
    int* offsets = (int*)w;  w += 256;
    int* hist    = (int*)w;  w += ROUTER_BLOCKS * N_EXPERTS * 4;
    int* eidx    = (int*)w;  w += N_TOKENS * 4;
    int* lpos    = (int*)w;  w += N_TOKENS * 4;
    int* order   = (int*)w;  w += N_TOKENS * 4;
    float* prob  = (float*)w; w += N_TOKENS * 4;
    _Float16* act_h  = (_Float16*)w; w += (size_t)N_TOKENS * D_IN * 2;
    _Float16* encT   = (_Float16*)w; w += (size_t)N_EXPERTS * D_IN * EXPERT_DIM * 2;
    _Float16* decT   = (_Float16*)w; w += (size_t)N_EXPERTS * D_IN * EXPERT_DIM * 2;
    _Float16* latent = (_Float16*)w; w += (size_t)(N_TOKENS + BM) * EXPERT_DIM * 2;

    router_kernel<<<ROUTER_BLOCKS, 256, 0, stream>>>(act, router_b, router, prob, lpos, eidx, hist);
    scan_kernel<<<1, 256, 0, stream>>>(hist, counts, offsets);
    order_kernel<<<N_TOKENS / 256, 256, 0, stream>>>(eidx, lpos, hist, order);

    convert_act<<<N_TOKENS * D_IN / (256 * 8), 256, 0, stream>>>(act, act_h);
    transpose_to_half<<<dim3(EXPERT_DIM / 64, D_IN / 64, N_EXPERTS), 256, 0, stream>>>(enc, encT, D_IN, EXPERT_DIM);
    transpose_to_half<<<dim3(D_IN / 64, EXPERT_DIM / 64, N_EXPERTS), 256, 0, stream>>>(dec, decT, EXPERT_DIM, D_IN);

    encode_kernel<<<16384, 256, 0, stream>>>(act_h, encT, order, counts, offsets, latent);
    decode_kernel<<<6144, 256, 0, stream>>>(latent, decT, order, counts, offsets, prob, pre_b, out);
}